// Round 17
// baseline (118.027 us; speedup 1.0000x reference)
//
#include <hip/hip_runtime.h>
#include <hip/hip_fp16.h>
#include <math.h>

// Problem: B=4, L=1024, C1=1024, C2=1024, K=32, K_IN=32, g=256.
// N = B*L = 4096 rows. All f32.
//
// ws layout (floats):
//   wT16    [524288 f32-equiv]     off 0        (fp16 W^T, 2MB, final gathers)
//   W16     [524288 f32-equiv]     off 524288   (fp16 W, 2MB, final gathers)
//   whl     [524288 f32-equiv]     off 1048576  (bf16 hi/lo split lin_w, 2MB)
//   xc      [2][4096*256]          off 1572864
//   partials[256][4][256]          off 3670016
//   sc      [2][2][256]            off 3932160
//   logits  [8192][1024]           off 3933184
//   xah     [1048576 f32-equiv]    off 12321792 (bf16 hi xa frags, 4MB)
//   xal     [1048576 f32-equiv]    off 13370368 (bf16 lo xa frags, 4MB)
// total ~14.4M floats = 57.7 MB

typedef __attribute__((ext_vector_type(8))) short short8;
typedef __attribute__((ext_vector_type(4))) float f32x4;
typedef __attribute__((ext_vector_type(2))) _Float16 half2_t;

__device__ __forceinline__ unsigned int ford(float f) {
    unsigned int b = __float_as_uint(f);
    return (b & 0x80000000u) ? ~b : (b | 0x80000000u);
}

__device__ __forceinline__ unsigned int pkrtz(float a, float b) {
    auto p = __builtin_amdgcn_cvt_pkrtz(a, b);  // __fp16 ext_vector(2)
    return *(const unsigned int*)&p;
}

// ---------------- fused prep: W->fp16 (straight+transposed) + lin_w split ----
__global__ __launch_bounds__(256) void prep_k(
    const float* __restrict__ W,
    const float* __restrict__ so_lw, const float* __restrict__ si_lw,
    const float* __restrict__ x,
    const float* __restrict__ so_cw, const float* __restrict__ so_cb,
    const float* __restrict__ si_cw, const float* __restrict__ si_cb,
    __half* __restrict__ wT16, __half* __restrict__ W16,
    unsigned short* __restrict__ whl,
    float* __restrict__ xc, float* __restrict__ partials) {
    int bid = blockIdx.x;
    int t = threadIdx.x;
    if (bid < 1024) {
        __shared__ float tile[32][33];
        int c0 = (bid & 31) * 32, r0 = (bid >> 5) * 32;
        int tx = t & 31, ty = t >> 5;  // ty 0..7
#pragma unroll
        for (int i = 0; i < 32; i += 8) {
            float v = W[(size_t)(r0 + ty + i) * 1024 + c0 + tx];
            tile[ty + i][tx] = v;
            W16[(size_t)(r0 + ty + i) * 1024 + c0 + tx] = __float2half_rn(v);
        }
        __syncthreads();
#pragma unroll
        for (int i = 0; i < 32; i += 8)
            wT16[(size_t)(c0 + ty + i) * 1024 + r0 + tx] =
                __float2half_rn(tile[tx][ty + i]);
    } else if (bid < 1280) {
        int g = (bid - 1024) * 256 + t;  // 0..65535
        int br = g >> 15;
        int rem = g & 32767;
        int ct = rem >> 9;
        int kt = (rem >> 6) & 7;
        int l  = rem & 63;
        int col = ct * 16 + (l & 15);
        int ks  = kt * 32 + (l >> 4) * 8;
        const float* lw = (br ? si_lw : so_lw) + (size_t)col * 256 + ks;
        float4 v0 = *(const float4*)lw;
        float4 v1 = *(const float4*)(lw + 4);
        unsigned hh[8], ll[8];
#pragma unroll
        for (int j = 0; j < 8; ++j) {
            float a = j < 4 ? (&v0.x)[j] : (&v1.x)[j - 4];
            unsigned b = __float_as_uint(a);
            unsigned rh = (b + 0x7FFFu + ((b >> 16) & 1u)) & 0xFFFF0000u;
            hh[j] = rh >> 16;
            float res = a - __uint_as_float(rh);
            unsigned c = __float_as_uint(res);
            unsigned rl = (c + 0x7FFFu + ((c >> 16) & 1u)) & 0xFFFF0000u;
            ll[j] = rl >> 16;
        }
        uint4 ph, pl;
        ph.x = hh[0] | (hh[1] << 16); ph.y = hh[2] | (hh[3] << 16);
        ph.z = hh[4] | (hh[5] << 16); ph.w = hh[6] | (hh[7] << 16);
        pl.x = ll[0] | (ll[1] << 16); pl.y = ll[2] | (ll[3] << 16);
        pl.z = ll[4] | (ll[5] << 16); pl.w = ll[6] | (ll[7] << 16);
        size_t base = (((((size_t)br * 2 + 0) * 64 + ct) * 8 + kt) * 64 + l) * 8;
        size_t hstride = (size_t)64 * 8 * 64 * 8;
        *(uint4*)&whl[base]           = ph;
        *(uint4*)&whl[base + hstride] = pl;
    } else {
        int g = t;                     // channel 0..255
        int n0 = (bid - 1280) * 16;    // 256 blocks x 16 rows
        float4 wo = ((const float4*)so_cw)[g]; float bo = so_cb[g];
        float4 wi = ((const float4*)si_cw)[g]; float bi = si_cb[g];
        float so_s = 0.f, so_q = 0.f, si_s = 0.f, si_q = 0.f;
#pragma unroll
        for (int r = 0; r < 16; ++r) {
            int n = n0 + r;
            float4 xv = ((const float4*)x)[n * 256 + g];
            float co = fmaf(xv.x, wo.x, fmaf(xv.y, wo.y, fmaf(xv.z, wo.z, fmaf(xv.w, wo.w, bo))));
            float ci = fmaf(xv.x, wi.x, fmaf(xv.y, wi.y, fmaf(xv.z, wi.z, fmaf(xv.w, wi.w, bi))));
            xc[n * 256 + g] = co;
            xc[1048576 + n * 256 + g] = ci;
            so_s += co; so_q += co * co;
            si_s += ci; si_q += ci * ci;
        }
        int b = bid - 1280;
        partials[(b * 4 + 0) * 256 + g] = so_s;
        partials[(b * 4 + 1) * 256 + g] = so_q;
        partials[(b * 4 + 2) * 256 + g] = si_s;
        partials[(b * 4 + 3) * 256 + g] = si_q;
    }
}

// ---------------- finalize BN stats -> per-channel scale/shift ---------------
__global__ __launch_bounds__(256) void stats_k(
    const float* __restrict__ partials,
    const float* __restrict__ g_so, const float* __restrict__ b_so,
    const float* __restrict__ g_si, const float* __restrict__ b_si,
    float* __restrict__ sc) {
    int g = threadIdx.x;
    int br = blockIdx.x;  // 0 = so, 1 = si
    float s = 0.f, q = 0.f;
    for (int b = 0; b < 256; ++b) {
        s += partials[(b * 4 + br * 2 + 0) * 256 + g];
        q += partials[(b * 4 + br * 2 + 1) * 256 + g];
    }
    float mean = s * (1.f / 4096.f);
    float var  = q * (1.f / 4096.f) - mean * mean;  // biased, matches ref
    float rstd = rsqrtf(var + 1e-5f);
    float gm = br ? g_si[g] : g_so[g];
    float bt = br ? b_si[g] : b_so[g];
    float scale = gm * rstd;
    sc[br * 512 + g]       = scale;
    sc[br * 512 + 256 + g] = fmaf(-mean, scale, bt);
}

// ---------------- BN + exact GELU + bf16 hi/lo split -> xa MFMA A-fragments --
__global__ __launch_bounds__(256) void gelusplit_k(
    const float* __restrict__ xc, const float* __restrict__ sc,
    unsigned short* __restrict__ xah, unsigned short* __restrict__ xal) {
    int s = blockIdx.x * 256 + threadIdx.x;  // 0..262143
    int br  = s >> 17;
    int rem = s & 131071;
    int rtg = rem >> 9;
    int kt  = (rem >> 6) & 7;
    int l   = rem & 63;
    int row = rtg * 16 + (l & 15);
    int ks  = kt * 32 + (l >> 4) * 8;
    const float* xp  = xc + (size_t)br * 1048576 + (size_t)row * 256 + ks;
    const float* scp = sc + br * 512;
    float4 c0 = *(const float4*)xp;
    float4 c1 = *(const float4*)(xp + 4);
    float4 s0 = *(const float4*)(scp + ks);
    float4 s1 = *(const float4*)(scp + ks + 4);
    float4 h0 = *(const float4*)(scp + 256 + ks);
    float4 h1 = *(const float4*)(scp + 256 + ks + 4);
    unsigned hh[8], ll[8];
#pragma unroll
    for (int j = 0; j < 8; ++j) {
        float cv  = j < 4 ? (&c0.x)[j] : (&c1.x)[j - 4];
        float scl = j < 4 ? (&s0.x)[j] : (&s1.x)[j - 4];
        float shf = j < 4 ? (&h0.x)[j] : (&h1.x)[j - 4];
        float z = fmaf(cv, scl, shf);
        float a = 0.5f * z * (1.f + erff(z * 0.70710678f));
        unsigned b = __float_as_uint(a);
        unsigned rh = (b + 0x7FFFu + ((b >> 16) & 1u)) & 0xFFFF0000u;
        hh[j] = rh >> 16;
        float res = a - __uint_as_float(rh);
        unsigned cc = __float_as_uint(res);
        unsigned rl = (cc + 0x7FFFu + ((cc >> 16) & 1u)) & 0xFFFF0000u;
        ll[j] = rl >> 16;
    }
    uint4 ph, pl;
    ph.x = hh[0] | (hh[1] << 16); ph.y = hh[2] | (hh[3] << 16);
    ph.z = hh[4] | (hh[5] << 16); ph.w = hh[6] | (hh[7] << 16);
    pl.x = ll[0] | (ll[1] << 16); pl.y = ll[2] | (ll[3] << 16);
    pl.z = ll[4] | (ll[5] << 16); pl.w = ll[6] | (ll[7] << 16);
    *(uint4*)&xah[(size_t)s * 8] = ph;
    *(uint4*)&xal[(size_t)s * 8] = pl;
}

// ---------------- bf16x3-split MFMA logits GEMM ------------------------------
__global__ __launch_bounds__(256, 2) void logits_mfma2_k(
    const unsigned short* __restrict__ xah, const unsigned short* __restrict__ xal,
    const unsigned short* __restrict__ whl,
    const float* __restrict__ so_lb, const float* __restrict__ si_lb,
    float* __restrict__ logits) {
    int t = threadIdx.x;
    int bx = blockIdx.x;          // 64-row block
    int n0 = bx * 64;
    int cb = blockIdx.y;          // 256-col block
    int br = blockIdx.z;
    int wave = t >> 6, lane = t & 63;

    f32x4 acc[4][4];  // [ci][rt]
#pragma unroll
    for (int ci = 0; ci < 4; ++ci)
#pragma unroll
        for (int rt = 0; rt < 4; ++rt) acc[ci][rt] = (f32x4){0.f, 0.f, 0.f, 0.f};

    const size_t hstride = (size_t)64 * 8 * 64 * 8;
#pragma unroll 2
    for (int kt = 0; kt < 8; ++kt) {
        short8 Ah[4], Al[4];
#pragma unroll
        for (int rt = 0; rt < 4; ++rt) {
            size_t aoff = (((size_t)br * 256 + bx * 4 + rt) * 8 + kt) * 512 +
                          (size_t)lane * 8;
            Ah[rt] = *(const short8*)&xah[aoff];
            Al[rt] = *(const short8*)&xal[aoff];
        }
#pragma unroll
        for (int ci = 0; ci < 4; ++ci) {
            int ctg = cb * 16 + wave * 4 + ci;
            size_t boff = ((((size_t)br * 2 + 0) * 64 + ctg) * 8 + kt) * 512 +
                          (size_t)lane * 8;
            short8 Wh = *(const short8*)&whl[boff];
            short8 Wl = *(const short8*)&whl[boff + hstride];
#pragma unroll
            for (int rt = 0; rt < 4; ++rt) {
                acc[ci][rt] = __builtin_amdgcn_mfma_f32_16x16x32_bf16(Ah[rt], Wh, acc[ci][rt], 0, 0, 0);
                acc[ci][rt] = __builtin_amdgcn_mfma_f32_16x16x32_bf16(Ah[rt], Wl, acc[ci][rt], 0, 0, 0);
                acc[ci][rt] = __builtin_amdgcn_mfma_f32_16x16x32_bf16(Al[rt], Wh, acc[ci][rt], 0, 0, 0);
            }
        }
    }

    // C/D mapping (HW-verified): col = lane&15, row = (lane>>4)*4 + i
    const float* lb = br ? si_lb : so_lb;
#pragma unroll
    for (int ci = 0; ci < 4; ++ci) {
        int colg = cb * 256 + (wave * 4 + ci) * 16 + (lane & 15);
        float lbv = lb[colg];
#pragma unroll
        for (int rt = 0; rt < 4; ++rt) {
#pragma unroll
            for (int i = 0; i < 4; ++i) {
                int row = n0 + rt * 16 + (lane >> 4) * 4 + i;
                logits[((size_t)br * 4096 + row) * 1024 + colg] = acc[ci][rt][i] + lbv;
            }
        }
    }
}

// ---------------- fused topk + final (barrier-free topk) ---------------------
// Block n: waves 0/1 run the radix top-32 for row-branches n (out) and 4096+n
// (in) ENTIRELY without block barriers -- the histograms are wave-private and
// LDS ops from a single wave execute in program order. Waves 2/3 just compute
// their fp16 x registers and wait at B1. Final phase: fdot2 gathered dots +
// fp16 axpys. 4 barriers total (was 13).
__global__ __launch_bounds__(256) void topkfinal_k(
    const float* __restrict__ logits, const float* __restrict__ x,
    const __half* __restrict__ wT16, const __half* __restrict__ W16,
    const float* __restrict__ bias, float* __restrict__ out) {
    int n = blockIdx.x, t = threadIdx.x, wave = t >> 6, lane = t & 63;
    __shared__ float xr[1024];          // output scratch only
    __shared__ float dres[32];
    __shared__ unsigned int gidx[32]; __shared__ float gval[32];
    __shared__ unsigned int iidx[32]; __shared__ float ival[32];
    __shared__ unsigned int hist[2][256];
    __shared__ unsigned int wcnt[2];

    // ---- per-lane x in fp16 registers (all waves; overlaps the topk) ----
    unsigned int xh[8];
    {
        const float4* xg = (const float4*)(x + (size_t)n * 1024);
#pragma unroll
        for (int q = 0; q < 2; ++q) {
            float4 xa = xg[(q * 64 + lane) * 2];
            float4 xb = xg[(q * 64 + lane) * 2 + 1];
            xh[q * 4 + 0] = pkrtz(xa.x, xa.y);
            xh[q * 4 + 1] = pkrtz(xa.z, xa.w);
            xh[q * 4 + 2] = pkrtz(xb.x, xb.y);
            xh[q * 4 + 3] = pkrtz(xb.z, xb.w);
        }
    }

    if (wave < 2) {
        // ================= barrier-free wave-private top-32 =================
        float v[16];
        unsigned int kb[16];
        unsigned int* h = hist[wave];
        const float4* lg = (const float4*)(logits + ((size_t)wave * 4096 + n) * 1024);
#pragma unroll
        for (int q = 0; q < 4; ++q) {
            float4 f = lg[q * 64 + lane];
            v[q * 4 + 0] = f.x; v[q * 4 + 1] = f.y;
            v[q * 4 + 2] = f.z; v[q * 4 + 3] = f.w;
        }
        float rmax = v[0];
#pragma unroll
        for (int i = 1; i < 16; ++i) rmax = fmaxf(rmax, v[i]);
#pragma unroll
        for (int s = 32; s; s >>= 1) rmax = fmaxf(rmax, __shfl_xor(rmax, s));
        float rsum = 0.f;
#pragma unroll
        for (int i = 0; i < 16; ++i) rsum += __expf(v[i] - rmax);
#pragma unroll
        for (int s = 32; s; s >>= 1) rsum += __shfl_xor(rsum, s);
#pragma unroll
        for (int i = 0; i < 16; ++i) kb[i] = ford(v[i]);

        unsigned inmask = 0xFFFFu, need = 32, prefix = 0, lasth = 0;
#pragma unroll
        for (int level = 0; level < 3; ++level) {
            int shift = 24 - level * 8;
            ((uint4*)h)[lane] = make_uint4(0u, 0u, 0u, 0u);
#pragma unroll
            for (int i = 0; i < 16; ++i)
                if ((inmask >> i) & 1u) atomicAdd(&h[(kb[i] >> shift) & 0xFFu], 1u);
            uint4 hv = ((const uint4*)h)[lane];
            unsigned sl = hv.x + hv.y + hv.z + hv.w;
            unsigned S = sl;
#pragma unroll
            for (int off = 1; off < 64; off <<= 1) {
                unsigned o = __shfl_down(S, off);
                if (lane + off < 64) S += o;
            }
            unsigned above = S - sl;
            unsigned cg3 = above + hv.w;
            unsigned cg2 = cg3 + hv.z;
            unsigned cg1 = cg2 + hv.y;
            unsigned cg0 = cg1 + hv.x;
            unsigned pack = 0;
            if      (cg3 >= need) pack = ((4u * lane + 3u) << 12) | cg3;
            else if (cg2 >= need) pack = ((4u * lane + 2u) << 12) | cg2;
            else if (cg1 >= need) pack = ((4u * lane + 1u) << 12) | cg1;
            else if (cg0 >= need) pack = ((4u * lane + 0u) << 12) | cg0;
#pragma unroll
            for (int s = 32; s; s >>= 1) {
                unsigned o = __shfl_xor(pack, s);
                pack = o > pack ? o : pack;
            }
            unsigned bstar = pack >> 12, cstar = pack & 0xFFFu;
            unsigned hstar = h[bstar];
            need -= (cstar - hstar);
            prefix = (prefix << 8) | bstar;
            lasth = hstar;
            unsigned nm = 0;
#pragma unroll
            for (int i = 0; i < 16; ++i)
                if (((inmask >> i) & 1u) && ((kb[i] >> shift) & 0xFFu) == bstar)
                    nm |= 1u << i;
            inmask = nm;
        }

        unsigned winmask = 0;
        if (lasth == need) {
            winmask = inmask;
        } else {
            unsigned avail = inmask;
            unsigned long long best = 0ULL;
#pragma unroll
            for (int i = 0; i < 16; ++i)
                if ((avail >> i) & 1u) {
                    int j = (i >> 2) * 256 + lane * 4 + (i & 3);
                    unsigned long long k64 =
                        ((unsigned long long)kb[i] << 32) | (unsigned int)(~j);
                    best = k64 > best ? k64 : best;
                }
            for (unsigned k = 0; k < need; ++k) {
                unsigned long long w = best;
#pragma unroll
                for (int s = 32; s; s >>= 1) {
                    unsigned long long o = __shfl_xor(w, s);
                    if (o > w) w = o;
                }
                if (best == w) {
                    unsigned long long nb = 0ULL;
#pragma unroll
                    for (int i = 0; i < 16; ++i)
                        if ((avail >> i) & 1u) {
                            int j = (i >> 2) * 256 + lane * 4 + (i & 3);
                            unsigned long long k64 =
                                ((unsigned long long)kb[i] << 32) | (unsigned int)(~j);
                            if (k64 == w) { winmask |= 1u << i; avail &= ~(1u << i); }
                            else nb = k64 > nb ? k64 : nb;
                        }
                    best = nb;
                }
            }
        }
        if (lane == 0) wcnt[wave] = 0;
        unsigned int* oid = wave ? iidx : gidx;
        float*        ovl = wave ? ival : gval;
#pragma unroll
        for (int i = 0; i < 16; ++i) {
            bool wn = ((kb[i] >> 8) > prefix) || ((winmask >> i) & 1u);
            if (wn) {
                unsigned slot = atomicAdd(&wcnt[wave], 1u);
                int j = (i >> 2) * 256 + lane * 4 + (i & 3);
                oid[slot] = (unsigned int)j;
                ovl[slot] = __expf(v[i] - rmax) / rsum;
            }
        }
    }
    __syncthreads();  // B1: topk results ready

    if (t < 32) ival[t] *= x[(size_t)n * 1024 + iidx[t]];  // g_k = s_v_in * x[c_k]

    // out-branch: 32 gathered fp16 dot products via v_dot2_f32_f16, 8 per wave
#pragma unroll
    for (int d8 = 0; d8 < 8; ++d8) {
        int d = wave * 8 + d8;
        unsigned rowb = (unsigned)__builtin_amdgcn_readfirstlane(gidx[d]);
        const uint4* wrow = (const uint4*)(wT16 + (size_t)rowb * 1024);
        float s = 0.f;
#pragma unroll
        for (int q = 0; q < 2; ++q) {
            uint4 wv = wrow[q * 64 + lane];
            s = __builtin_amdgcn_fdot2(*(const half2_t*)&wv.x,
                                       *(const half2_t*)&xh[q * 4 + 0], s, false);
            s = __builtin_amdgcn_fdot2(*(const half2_t*)&wv.y,
                                       *(const half2_t*)&xh[q * 4 + 1], s, false);
            s = __builtin_amdgcn_fdot2(*(const half2_t*)&wv.z,
                                       *(const half2_t*)&xh[q * 4 + 2], s, false);
            s = __builtin_amdgcn_fdot2(*(const half2_t*)&wv.w,
                                       *(const half2_t*)&xh[q * 4 + 3], s, false);
        }
#pragma unroll
        for (int sft = 32; sft; sft >>= 1) s += __shfl_xor(s, sft);
        if (lane == 0) dres[d] = s * gval[d];
    }
    __syncthreads();  // B2: ival final, dres written

    // in-branch + bias: 32 fp16 axpys, thread t owns cols 4t..4t+3
    float4 acc = ((const float4*)bias)[t];
    for (int k = 0; k < 32; ++k) {
        float g = ival[k];
        unsigned c = (unsigned)__builtin_amdgcn_readfirstlane(iidx[k]);
        uint2 wv = ((const uint2*)(W16 + (size_t)c * 1024))[t];
        float2 f0 = __half22float2(*(const __half2*)&wv.x);
        float2 f1 = __half22float2(*(const __half2*)&wv.y);
        acc.x = fmaf(g, f0.x, acc.x); acc.y = fmaf(g, f0.y, acc.y);
        acc.z = fmaf(g, f1.x, acc.z); acc.w = fmaf(g, f1.y, acc.w);
    }
    ((float4*)xr)[t] = acc;
    __syncthreads();  // B3
    if (t < 32) xr[gidx[t]] += dres[t];  // unique indices, no race
    __syncthreads();  // B4
    ((float4*)(out + (size_t)n * 1024))[t] = ((float4*)xr)[t];
}

extern "C" void kernel_launch(void* const* d_in, const int* in_sizes, int n_in,
                              void* d_out, int out_size, void* d_ws, size_t ws_size,
                              hipStream_t stream) {
    (void)in_sizes; (void)n_in; (void)out_size; (void)ws_size;
    const float* x        = (const float*)d_in[0];
    const float* W        = (const float*)d_in[1];
    const float* bias     = (const float*)d_in[2];
    const float* so_cw    = (const float*)d_in[3];
    const float* so_cb    = (const float*)d_in[4];
    const float* so_gm    = (const float*)d_in[5];
    const float* so_bt    = (const float*)d_in[6];
    const float* so_lw    = (const float*)d_in[7];
    const float* so_lb    = (const float*)d_in[8];
    const float* si_cw    = (const float*)d_in[9];
    const float* si_cb    = (const float*)d_in[10];
    const float* si_gm    = (const float*)d_in[11];
    const float* si_bt    = (const float*)d_in[12];
    const float* si_lw    = (const float*)d_in[13];
    const float* si_lb    = (const float*)d_in[14];
    float* out = (float*)d_out;

    float* ws       = (float*)d_ws;
    __half* wT16    = (__half*)ws;                      // 1M halves (2MB)
    __half* W16     = (__half*)(ws + 524288);           // 1M halves (2MB)
    unsigned short* whl = (unsigned short*)(ws + 1048576);  // 1M ushorts
    float* xc       = ws + 1572864;             // 2 x 1048576
    float* partials = ws + 3670016;             // 262144
    float* sc       = ws + 3932160;             // 1024
    float* logits   = ws + 3933184;             // 8388608
    unsigned short* xah = (unsigned short*)(ws + 12321792);  // 2097152 ushorts
    unsigned short* xal = (unsigned short*)(ws + 13370368);  // 2097152 ushorts

    prep_k<<<1536, 256, 0, stream>>>(W, so_lw, si_lw, x, so_cw, so_cb, si_cw, si_cb,
                                     wT16, W16, whl, xc, partials);
    stats_k<<<2, 256, 0, stream>>>(partials, so_gm, so_bt, si_gm, si_bt, sc);
    gelusplit_k<<<1024, 256, 0, stream>>>(xc, sc, xah, xal);
    logits_mfma2_k<<<dim3(64, 4, 2), 256, 0, stream>>>(xah, xal, whl, so_lb, si_lb, logits);
    topkfinal_k<<<4096, 256, 0, stream>>>(logits, x, wT16, W16, bias, out);
}

// Round 18
// 100.844 us; speedup vs baseline: 1.1704x; 1.1704x over previous
//
#include <hip/hip_runtime.h>
#include <hip/hip_fp16.h>
#include <math.h>

// Problem: B=4, L=1024, C1=1024, C2=1024, K=32, K_IN=32, g=256.
// N = B*L = 4096 rows. All f32.
//
// ws layout (floats):
//   wT16    [524288 f32-equiv]     off 0        (fp16 W^T, 2MB, final gathers)
//   W16     [524288 f32-equiv]     off 524288   (fp16 W, 2MB, final gathers)
//   whl     [524288 f32-equiv]     off 1048576  (bf16 hi/lo split lin_w, 2MB)
//   xc      [2][4096*256]          off 1572864
//   partials[256][4][256]          off 3670016
//   sc      [2][2][256]            off 3932160
//   logits  [8192][1024]           off 3933184
//   xah     [1048576 f32-equiv]    off 12321792 (bf16 hi xa frags, 4MB)
//   xal     [1048576 f32-equiv]    off 13370368 (bf16 lo xa frags, 4MB)
// total ~14.4M floats = 57.7 MB

typedef __attribute__((ext_vector_type(8))) short short8;
typedef __attribute__((ext_vector_type(4))) float f32x4;
typedef __attribute__((ext_vector_type(2))) _Float16 half2_t;

__device__ __forceinline__ unsigned int ford(float f) {
    unsigned int b = __float_as_uint(f);
    return (b & 0x80000000u) ? ~b : (b | 0x80000000u);
}

__device__ __forceinline__ unsigned int pkrtz(float a, float b) {
    auto p = __builtin_amdgcn_cvt_pkrtz(a, b);  // __fp16 ext_vector(2)
    return *(const unsigned int*)&p;
}

// ---------------- fused prep: W->fp16 (straight+transposed) + lin_w split ----
__global__ __launch_bounds__(256) void prep_k(
    const float* __restrict__ W,
    const float* __restrict__ so_lw, const float* __restrict__ si_lw,
    const float* __restrict__ x,
    const float* __restrict__ so_cw, const float* __restrict__ so_cb,
    const float* __restrict__ si_cw, const float* __restrict__ si_cb,
    __half* __restrict__ wT16, __half* __restrict__ W16,
    unsigned short* __restrict__ whl,
    float* __restrict__ xc, float* __restrict__ partials) {
    int bid = blockIdx.x;
    int t = threadIdx.x;
    if (bid < 1024) {
        __shared__ float tile[32][33];
        int c0 = (bid & 31) * 32, r0 = (bid >> 5) * 32;
        int tx = t & 31, ty = t >> 5;  // ty 0..7
#pragma unroll
        for (int i = 0; i < 32; i += 8) {
            float v = W[(size_t)(r0 + ty + i) * 1024 + c0 + tx];
            tile[ty + i][tx] = v;
            W16[(size_t)(r0 + ty + i) * 1024 + c0 + tx] = __float2half_rn(v);
        }
        __syncthreads();
#pragma unroll
        for (int i = 0; i < 32; i += 8)
            wT16[(size_t)(c0 + ty + i) * 1024 + r0 + tx] =
                __float2half_rn(tile[tx][ty + i]);
    } else if (bid < 1280) {
        int g = (bid - 1024) * 256 + t;  // 0..65535
        int br = g >> 15;
        int rem = g & 32767;
        int ct = rem >> 9;
        int kt = (rem >> 6) & 7;
        int l  = rem & 63;
        int col = ct * 16 + (l & 15);
        int ks  = kt * 32 + (l >> 4) * 8;
        const float* lw = (br ? si_lw : so_lw) + (size_t)col * 256 + ks;
        float4 v0 = *(const float4*)lw;
        float4 v1 = *(const float4*)(lw + 4);
        unsigned hh[8], ll[8];
#pragma unroll
        for (int j = 0; j < 8; ++j) {
            float a = j < 4 ? (&v0.x)[j] : (&v1.x)[j - 4];
            unsigned b = __float_as_uint(a);
            unsigned rh = (b + 0x7FFFu + ((b >> 16) & 1u)) & 0xFFFF0000u;
            hh[j] = rh >> 16;
            float res = a - __uint_as_float(rh);
            unsigned c = __float_as_uint(res);
            unsigned rl = (c + 0x7FFFu + ((c >> 16) & 1u)) & 0xFFFF0000u;
            ll[j] = rl >> 16;
        }
        uint4 ph, pl;
        ph.x = hh[0] | (hh[1] << 16); ph.y = hh[2] | (hh[3] << 16);
        ph.z = hh[4] | (hh[5] << 16); ph.w = hh[6] | (hh[7] << 16);
        pl.x = ll[0] | (ll[1] << 16); pl.y = ll[2] | (ll[3] << 16);
        pl.z = ll[4] | (ll[5] << 16); pl.w = ll[6] | (ll[7] << 16);
        size_t base = (((((size_t)br * 2 + 0) * 64 + ct) * 8 + kt) * 64 + l) * 8;
        size_t hstride = (size_t)64 * 8 * 64 * 8;
        *(uint4*)&whl[base]           = ph;
        *(uint4*)&whl[base + hstride] = pl;
    } else {
        int g = t;                     // channel 0..255
        int n0 = (bid - 1280) * 16;    // 256 blocks x 16 rows
        float4 wo = ((const float4*)so_cw)[g]; float bo = so_cb[g];
        float4 wi = ((const float4*)si_cw)[g]; float bi = si_cb[g];
        float so_s = 0.f, so_q = 0.f, si_s = 0.f, si_q = 0.f;
#pragma unroll
        for (int r = 0; r < 16; ++r) {
            int n = n0 + r;
            float4 xv = ((const float4*)x)[n * 256 + g];
            float co = fmaf(xv.x, wo.x, fmaf(xv.y, wo.y, fmaf(xv.z, wo.z, fmaf(xv.w, wo.w, bo))));
            float ci = fmaf(xv.x, wi.x, fmaf(xv.y, wi.y, fmaf(xv.z, wi.z, fmaf(xv.w, wi.w, bi))));
            xc[n * 256 + g] = co;
            xc[1048576 + n * 256 + g] = ci;
            so_s += co; so_q += co * co;
            si_s += ci; si_q += ci * ci;
        }
        int b = bid - 1280;
        partials[(b * 4 + 0) * 256 + g] = so_s;
        partials[(b * 4 + 1) * 256 + g] = so_q;
        partials[(b * 4 + 2) * 256 + g] = si_s;
        partials[(b * 4 + 3) * 256 + g] = si_q;
    }
}

// ---------------- finalize BN stats -> per-channel scale/shift ---------------
__global__ __launch_bounds__(256) void stats_k(
    const float* __restrict__ partials,
    const float* __restrict__ g_so, const float* __restrict__ b_so,
    const float* __restrict__ g_si, const float* __restrict__ b_si,
    float* __restrict__ sc) {
    int g = threadIdx.x;
    int br = blockIdx.x;  // 0 = so, 1 = si
    float s = 0.f, q = 0.f;
    for (int b = 0; b < 256; ++b) {
        s += partials[(b * 4 + br * 2 + 0) * 256 + g];
        q += partials[(b * 4 + br * 2 + 1) * 256 + g];
    }
    float mean = s * (1.f / 4096.f);
    float var  = q * (1.f / 4096.f) - mean * mean;  // biased, matches ref
    float rstd = rsqrtf(var + 1e-5f);
    float gm = br ? g_si[g] : g_so[g];
    float bt = br ? b_si[g] : b_so[g];
    float scale = gm * rstd;
    sc[br * 512 + g]       = scale;
    sc[br * 512 + 256 + g] = fmaf(-mean, scale, bt);
}

// ---------------- BN + exact GELU + bf16 hi/lo split -> xa MFMA A-fragments --
__global__ __launch_bounds__(256) void gelusplit_k(
    const float* __restrict__ xc, const float* __restrict__ sc,
    unsigned short* __restrict__ xah, unsigned short* __restrict__ xal) {
    int s = blockIdx.x * 256 + threadIdx.x;  // 0..262143
    int br  = s >> 17;
    int rem = s & 131071;
    int rtg = rem >> 9;
    int kt  = (rem >> 6) & 7;
    int l   = rem & 63;
    int row = rtg * 16 + (l & 15);
    int ks  = kt * 32 + (l >> 4) * 8;
    const float* xp  = xc + (size_t)br * 1048576 + (size_t)row * 256 + ks;
    const float* scp = sc + br * 512;
    float4 c0 = *(const float4*)xp;
    float4 c1 = *(const float4*)(xp + 4);
    float4 s0 = *(const float4*)(scp + ks);
    float4 s1 = *(const float4*)(scp + ks + 4);
    float4 h0 = *(const float4*)(scp + 256 + ks);
    float4 h1 = *(const float4*)(scp + 256 + ks + 4);
    unsigned hh[8], ll[8];
#pragma unroll
    for (int j = 0; j < 8; ++j) {
        float cv  = j < 4 ? (&c0.x)[j] : (&c1.x)[j - 4];
        float scl = j < 4 ? (&s0.x)[j] : (&s1.x)[j - 4];
        float shf = j < 4 ? (&h0.x)[j] : (&h1.x)[j - 4];
        float z = fmaf(cv, scl, shf);
        float a = 0.5f * z * (1.f + erff(z * 0.70710678f));
        unsigned b = __float_as_uint(a);
        unsigned rh = (b + 0x7FFFu + ((b >> 16) & 1u)) & 0xFFFF0000u;
        hh[j] = rh >> 16;
        float res = a - __uint_as_float(rh);
        unsigned cc = __float_as_uint(res);
        unsigned rl = (cc + 0x7FFFu + ((cc >> 16) & 1u)) & 0xFFFF0000u;
        ll[j] = rl >> 16;
    }
    uint4 ph, pl;
    ph.x = hh[0] | (hh[1] << 16); ph.y = hh[2] | (hh[3] << 16);
    ph.z = hh[4] | (hh[5] << 16); ph.w = hh[6] | (hh[7] << 16);
    pl.x = ll[0] | (ll[1] << 16); pl.y = ll[2] | (ll[3] << 16);
    pl.z = ll[4] | (ll[5] << 16); pl.w = ll[6] | (ll[7] << 16);
    *(uint4*)&xah[(size_t)s * 8] = ph;
    *(uint4*)&xal[(size_t)s * 8] = pl;
}

// ---------------- bf16x3-split MFMA logits GEMM ------------------------------
__global__ __launch_bounds__(256, 2) void logits_mfma2_k(
    const unsigned short* __restrict__ xah, const unsigned short* __restrict__ xal,
    const unsigned short* __restrict__ whl,
    const float* __restrict__ so_lb, const float* __restrict__ si_lb,
    float* __restrict__ logits) {
    int t = threadIdx.x;
    int bx = blockIdx.x;          // 64-row block
    int n0 = bx * 64;
    int cb = blockIdx.y;          // 256-col block
    int br = blockIdx.z;
    int wave = t >> 6, lane = t & 63;

    f32x4 acc[4][4];  // [ci][rt]
#pragma unroll
    for (int ci = 0; ci < 4; ++ci)
#pragma unroll
        for (int rt = 0; rt < 4; ++rt) acc[ci][rt] = (f32x4){0.f, 0.f, 0.f, 0.f};

    const size_t hstride = (size_t)64 * 8 * 64 * 8;
#pragma unroll 2
    for (int kt = 0; kt < 8; ++kt) {
        short8 Ah[4], Al[4];
#pragma unroll
        for (int rt = 0; rt < 4; ++rt) {
            size_t aoff = (((size_t)br * 256 + bx * 4 + rt) * 8 + kt) * 512 +
                          (size_t)lane * 8;
            Ah[rt] = *(const short8*)&xah[aoff];
            Al[rt] = *(const short8*)&xal[aoff];
        }
#pragma unroll
        for (int ci = 0; ci < 4; ++ci) {
            int ctg = cb * 16 + wave * 4 + ci;
            size_t boff = ((((size_t)br * 2 + 0) * 64 + ctg) * 8 + kt) * 512 +
                          (size_t)lane * 8;
            short8 Wh = *(const short8*)&whl[boff];
            short8 Wl = *(const short8*)&whl[boff + hstride];
#pragma unroll
            for (int rt = 0; rt < 4; ++rt) {
                acc[ci][rt] = __builtin_amdgcn_mfma_f32_16x16x32_bf16(Ah[rt], Wh, acc[ci][rt], 0, 0, 0);
                acc[ci][rt] = __builtin_amdgcn_mfma_f32_16x16x32_bf16(Ah[rt], Wl, acc[ci][rt], 0, 0, 0);
                acc[ci][rt] = __builtin_amdgcn_mfma_f32_16x16x32_bf16(Al[rt], Wh, acc[ci][rt], 0, 0, 0);
            }
        }
    }

    // C/D mapping (HW-verified): col = lane&15, row = (lane>>4)*4 + i
    const float* lb = br ? si_lb : so_lb;
#pragma unroll
    for (int ci = 0; ci < 4; ++ci) {
        int colg = cb * 256 + (wave * 4 + ci) * 16 + (lane & 15);
        float lbv = lb[colg];
#pragma unroll
        for (int rt = 0; rt < 4; ++rt) {
#pragma unroll
            for (int i = 0; i < 4; ++i) {
                int row = n0 + rt * 16 + (lane >> 4) * 4 + i;
                logits[((size_t)br * 4096 + row) * 1024 + colg] = acc[ci][rt][i] + lbv;
            }
        }
    }
}

// ---------------- fused topk + final: 2 rows/block, 1 topk per wave ----------
// Block handles rows r0=2*bid, r0+1. Wave w runs the COMPLETE barrier-free
// top-32 for row-branch (w&1)*4096 + r0 + (w>>1) -- all 4 waves do equal topk
// work (no idle waves). Then waves 0/1 compute row r0's 32 gathered dots
// (16 each), waves 2/3 row r0+1's; in-branch gives each thread 8 columns of
// one row. 4 barriers total.
__global__ __launch_bounds__(256) void topkfinal_k(
    const float* __restrict__ logits, const float* __restrict__ x,
    const __half* __restrict__ wT16, const __half* __restrict__ W16,
    const float* __restrict__ bias, float* __restrict__ out) {
    int t = threadIdx.x, wave = t >> 6, lane = t & 63;
    int r0 = blockIdx.x * 2;
    int ri = wave >> 1;            // this wave's row (0/1)
    int branch = wave & 1;         // 0 = out-branch topk, 1 = in-branch topk
    __shared__ float xr[2][1024];  // output scratch
    __shared__ float dres[2][32];
    __shared__ unsigned int gidx[2][32]; __shared__ float gval[2][32];
    __shared__ unsigned int iidx[2][32]; __shared__ float ival[2][32];
    __shared__ unsigned int hist[4][256];
    __shared__ unsigned int wcnt[4];

    {
        // ================= barrier-free wave-private top-32 =================
        float v[16];
        unsigned int kb[16];
        unsigned int* h = hist[wave];
        const float4* lg =
            (const float4*)(logits + ((size_t)branch * 4096 + r0 + ri) * 1024);
#pragma unroll
        for (int q = 0; q < 4; ++q) {
            float4 f = lg[q * 64 + lane];
            v[q * 4 + 0] = f.x; v[q * 4 + 1] = f.y;
            v[q * 4 + 2] = f.z; v[q * 4 + 3] = f.w;
        }
        float rmax = v[0];
#pragma unroll
        for (int i = 1; i < 16; ++i) rmax = fmaxf(rmax, v[i]);
#pragma unroll
        for (int s = 32; s; s >>= 1) rmax = fmaxf(rmax, __shfl_xor(rmax, s));
        float rsum = 0.f;
#pragma unroll
        for (int i = 0; i < 16; ++i) rsum += __expf(v[i] - rmax);
#pragma unroll
        for (int s = 32; s; s >>= 1) rsum += __shfl_xor(rsum, s);
#pragma unroll
        for (int i = 0; i < 16; ++i) kb[i] = ford(v[i]);

        unsigned inmask = 0xFFFFu, need = 32, prefix = 0, lasth = 0;
#pragma unroll
        for (int level = 0; level < 3; ++level) {
            int shift = 24 - level * 8;
            ((uint4*)h)[lane] = make_uint4(0u, 0u, 0u, 0u);
#pragma unroll
            for (int i = 0; i < 16; ++i)
                if ((inmask >> i) & 1u) atomicAdd(&h[(kb[i] >> shift) & 0xFFu], 1u);
            uint4 hv = ((const uint4*)h)[lane];
            unsigned sl = hv.x + hv.y + hv.z + hv.w;
            unsigned S = sl;
#pragma unroll
            for (int off = 1; off < 64; off <<= 1) {
                unsigned o = __shfl_down(S, off);
                if (lane + off < 64) S += o;
            }
            unsigned above = S - sl;
            unsigned cg3 = above + hv.w;
            unsigned cg2 = cg3 + hv.z;
            unsigned cg1 = cg2 + hv.y;
            unsigned cg0 = cg1 + hv.x;
            unsigned pack = 0;
            if      (cg3 >= need) pack = ((4u * lane + 3u) << 12) | cg3;
            else if (cg2 >= need) pack = ((4u * lane + 2u) << 12) | cg2;
            else if (cg1 >= need) pack = ((4u * lane + 1u) << 12) | cg1;
            else if (cg0 >= need) pack = ((4u * lane + 0u) << 12) | cg0;
#pragma unroll
            for (int s = 32; s; s >>= 1) {
                unsigned o = __shfl_xor(pack, s);
                pack = o > pack ? o : pack;
            }
            unsigned bstar = pack >> 12, cstar = pack & 0xFFFu;
            unsigned hstar = h[bstar];
            need -= (cstar - hstar);
            prefix = (prefix << 8) | bstar;
            lasth = hstar;
            unsigned nm = 0;
#pragma unroll
            for (int i = 0; i < 16; ++i)
                if (((inmask >> i) & 1u) && ((kb[i] >> shift) & 0xFFu) == bstar)
                    nm |= 1u << i;
            inmask = nm;
        }

        unsigned winmask = 0;
        if (lasth == need) {
            winmask = inmask;
        } else {
            unsigned avail = inmask;
            unsigned long long best = 0ULL;
#pragma unroll
            for (int i = 0; i < 16; ++i)
                if ((avail >> i) & 1u) {
                    int j = (i >> 2) * 256 + lane * 4 + (i & 3);
                    unsigned long long k64 =
                        ((unsigned long long)kb[i] << 32) | (unsigned int)(~j);
                    best = k64 > best ? k64 : best;
                }
            for (unsigned k = 0; k < need; ++k) {
                unsigned long long w = best;
#pragma unroll
                for (int s = 32; s; s >>= 1) {
                    unsigned long long o = __shfl_xor(w, s);
                    if (o > w) w = o;
                }
                if (best == w) {
                    unsigned long long nb = 0ULL;
#pragma unroll
                    for (int i = 0; i < 16; ++i)
                        if ((avail >> i) & 1u) {
                            int j = (i >> 2) * 256 + lane * 4 + (i & 3);
                            unsigned long long k64 =
                                ((unsigned long long)kb[i] << 32) | (unsigned int)(~j);
                            if (k64 == w) { winmask |= 1u << i; avail &= ~(1u << i); }
                            else nb = k64 > nb ? k64 : nb;
                        }
                    best = nb;
                }
            }
        }
        if (lane == 0) wcnt[wave] = 0;
        unsigned int* oid = branch ? iidx[ri] : gidx[ri];
        float*        ovl = branch ? ival[ri] : gval[ri];
#pragma unroll
        for (int i = 0; i < 16; ++i) {
            bool wn = ((kb[i] >> 8) > prefix) || ((winmask >> i) & 1u);
            if (wn) {
                unsigned slot = atomicAdd(&wcnt[wave], 1u);
                int j = (i >> 2) * 256 + lane * 4 + (i & 3);
                oid[slot] = (unsigned int)j;
                ovl[slot] = __expf(v[i] - rmax) / rsum;
            }
        }
    }

    // ---- per-lane x of this wave's row in fp16 registers ----
    unsigned int xh[8];
    {
        const float4* xg = (const float4*)(x + (size_t)(r0 + ri) * 1024);
#pragma unroll
        for (int q = 0; q < 2; ++q) {
            float4 xa = xg[(q * 64 + lane) * 2];
            float4 xb = xg[(q * 64 + lane) * 2 + 1];
            xh[q * 4 + 0] = pkrtz(xa.x, xa.y);
            xh[q * 4 + 1] = pkrtz(xa.z, xa.w);
            xh[q * 4 + 2] = pkrtz(xb.x, xb.y);
            xh[q * 4 + 3] = pkrtz(xb.z, xb.w);
        }
    }
    __syncthreads();  // B1: all topk results ready

    if (t < 64) {
        int rr = t >> 5, k = t & 31;
        ival[rr][k] *= x[(size_t)(r0 + rr) * 1024 + iidx[rr][k]];
    }

    // out-branch: 16 gathered fp16 dots per wave (row ri), via v_dot2_f32_f16
#pragma unroll
    for (int d8 = 0; d8 < 16; ++d8) {
        int d = branch * 16 + d8;
        unsigned rowb = (unsigned)__builtin_amdgcn_readfirstlane(gidx[ri][d]);
        const uint4* wrow = (const uint4*)(wT16 + (size_t)rowb * 1024);
        float s = 0.f;
#pragma unroll
        for (int q = 0; q < 2; ++q) {
            uint4 wv = wrow[q * 64 + lane];
            s = __builtin_amdgcn_fdot2(*(const half2_t*)&wv.x,
                                       *(const half2_t*)&xh[q * 4 + 0], s, false);
            s = __builtin_amdgcn_fdot2(*(const half2_t*)&wv.y,
                                       *(const half2_t*)&xh[q * 4 + 1], s, false);
            s = __builtin_amdgcn_fdot2(*(const half2_t*)&wv.z,
                                       *(const half2_t*)&xh[q * 4 + 2], s, false);
            s = __builtin_amdgcn_fdot2(*(const half2_t*)&wv.w,
                                       *(const half2_t*)&xh[q * 4 + 3], s, false);
        }
#pragma unroll
        for (int sft = 32; sft; sft >>= 1) s += __shfl_xor(s, sft);
        if (lane == 0) dres[ri][d] = s * gval[ri][d];
    }
    __syncthreads();  // B2: ival final, dres written

    // in-branch + bias: thread t owns 8 cols of row (t>>7)
    {
        int rr = t >> 7, j0 = (t & 127) * 8;
        float4 accA = *(const float4*)&bias[j0];
        float4 accB = *(const float4*)&bias[j0 + 4];
        for (int k = 0; k < 32; ++k) {
            float g = ival[rr][k];
            unsigned c = (unsigned)__builtin_amdgcn_readfirstlane(iidx[rr][k]);
            uint4 wv = *(const uint4*)(W16 + (size_t)c * 1024 + j0);
            float2 f0 = __half22float2(*(const __half2*)&wv.x);
            float2 f1 = __half22float2(*(const __half2*)&wv.y);
            float2 f2 = __half22float2(*(const __half2*)&wv.z);
            float2 f3 = __half22float2(*(const __half2*)&wv.w);
            accA.x = fmaf(g, f0.x, accA.x); accA.y = fmaf(g, f0.y, accA.y);
            accA.z = fmaf(g, f1.x, accA.z); accA.w = fmaf(g, f1.y, accA.w);
            accB.x = fmaf(g, f2.x, accB.x); accB.y = fmaf(g, f2.y, accB.y);
            accB.z = fmaf(g, f3.x, accB.z); accB.w = fmaf(g, f3.y, accB.w);
        }
        *(float4*)&xr[rr][j0]     = accA;
        *(float4*)&xr[rr][j0 + 4] = accB;
    }
    __syncthreads();  // B3
    if (t < 64) {
        int rr = t >> 5, d = t & 31;
        xr[rr][gidx[rr][d]] += dres[rr][d];  // unique indices, no race
    }
    __syncthreads();  // B4
    {
        int rr = t >> 7, j0 = (t & 127) * 8;
        float* op = out + (size_t)(r0 + rr) * 1024 + j0;
        *(float4*)op       = *(const float4*)&xr[rr][j0];
        *(float4*)(op + 4) = *(const float4*)&xr[rr][j0 + 4];
    }
}

extern "C" void kernel_launch(void* const* d_in, const int* in_sizes, int n_in,
                              void* d_out, int out_size, void* d_ws, size_t ws_size,
                              hipStream_t stream) {
    (void)in_sizes; (void)n_in; (void)out_size; (void)ws_size;
    const float* x        = (const float*)d_in[0];
    const float* W        = (const float*)d_in[1];
    const float* bias     = (const float*)d_in[2];
    const float* so_cw    = (const float*)d_in[3];
    const float* so_cb    = (const float*)d_in[4];
    const float* so_gm    = (const float*)d_in[5];
    const float* so_bt    = (const float*)d_in[6];
    const float* so_lw    = (const float*)d_in[7];
    const float* so_lb    = (const float*)d_in[8];
    const float* si_cw    = (const float*)d_in[9];
    const float* si_cb    = (const float*)d_in[10];
    const float* si_gm    = (const float*)d_in[11];
    const float* si_bt    = (const float*)d_in[12];
    const float* si_lw    = (const float*)d_in[13];
    const float* si_lb    = (const float*)d_in[14];
    float* out = (float*)d_out;

    float* ws       = (float*)d_ws;
    __half* wT16    = (__half*)ws;                      // 1M halves (2MB)
    __half* W16     = (__half*)(ws + 524288);           // 1M halves (2MB)
    unsigned short* whl = (unsigned short*)(ws + 1048576);  // 1M ushorts
    float* xc       = ws + 1572864;             // 2 x 1048576
    float* partials = ws + 3670016;             // 262144
    float* sc       = ws + 3932160;             // 1024
    float* logits   = ws + 3933184;             // 8388608
    unsigned short* xah = (unsigned short*)(ws + 12321792);  // 2097152 ushorts
    unsigned short* xal = (unsigned short*)(ws + 13370368);  // 2097152 ushorts

    prep_k<<<1536, 256, 0, stream>>>(W, so_lw, si_lw, x, so_cw, so_cb, si_cw, si_cb,
                                     wT16, W16, whl, xc, partials);
    stats_k<<<2, 256, 0, stream>>>(partials, so_gm, so_bt, si_gm, si_bt, sc);
    gelusplit_k<<<1024, 256, 0, stream>>>(xc, sc, xah, xal);
    logits_mfma2_k<<<dim3(64, 4, 2), 256, 0, stream>>>(xah, xal, whl, so_lb, si_lb, logits);
    topkfinal_k<<<2048, 256, 0, stream>>>(logits, x, wT16, W16, bias, out);
}

// Round 19
// 99.214 us; speedup vs baseline: 1.1896x; 1.0164x over previous
//
#include <hip/hip_runtime.h>
#include <hip/hip_fp16.h>
#include <math.h>

// Problem: B=4, L=1024, C1=1024, C2=1024, K=32, K_IN=32, g=256.
// N = B*L = 4096 rows. All f32.
//
// ws layout (floats):
//   wT16    [524288 f32-equiv]     off 0        (fp16 W^T, 2MB, final gathers)
//   W16     [524288 f32-equiv]     off 524288   (fp16 W, 2MB, final gathers)
//   whl     [524288 f32-equiv]     off 1048576  (bf16 hi/lo split lin_w, 2MB)
//   xc      [2][4096*256]          off 1572864
//   partials[256][4][256]          off 3670016
//   sc      [2][2][256]            off 3932160
//   logits  [8192][1024]           off 3933184
//   xah     [1048576 f32-equiv]    off 12321792 (bf16 hi xa frags, 4MB)
//   xal     [1048576 f32-equiv]    off 13370368 (bf16 lo xa frags, 4MB)
// total ~14.4M floats = 57.7 MB

typedef __attribute__((ext_vector_type(8))) short short8;
typedef __attribute__((ext_vector_type(4))) float f32x4;
typedef __attribute__((ext_vector_type(2))) _Float16 half2_t;

__device__ __forceinline__ unsigned int ford(float f) {
    unsigned int b = __float_as_uint(f);
    return (b & 0x80000000u) ? ~b : (b | 0x80000000u);
}

__device__ __forceinline__ unsigned int pkrtz(float a, float b) {
    auto p = __builtin_amdgcn_cvt_pkrtz(a, b);  // __fp16 ext_vector(2)
    return *(const unsigned int*)&p;
}

// ---------------- fused prep: W->fp16 (straight+transposed) + lin_w split ----
__global__ __launch_bounds__(256) void prep_k(
    const float* __restrict__ W,
    const float* __restrict__ so_lw, const float* __restrict__ si_lw,
    const float* __restrict__ x,
    const float* __restrict__ so_cw, const float* __restrict__ so_cb,
    const float* __restrict__ si_cw, const float* __restrict__ si_cb,
    __half* __restrict__ wT16, __half* __restrict__ W16,
    unsigned short* __restrict__ whl,
    float* __restrict__ xc, float* __restrict__ partials) {
    int bid = blockIdx.x;
    int t = threadIdx.x;
    if (bid < 1024) {
        __shared__ float tile[32][33];
        int c0 = (bid & 31) * 32, r0 = (bid >> 5) * 32;
        int tx = t & 31, ty = t >> 5;  // ty 0..7
#pragma unroll
        for (int i = 0; i < 32; i += 8) {
            float v = W[(size_t)(r0 + ty + i) * 1024 + c0 + tx];
            tile[ty + i][tx] = v;
            W16[(size_t)(r0 + ty + i) * 1024 + c0 + tx] = __float2half_rn(v);
        }
        __syncthreads();
#pragma unroll
        for (int i = 0; i < 32; i += 8)
            wT16[(size_t)(c0 + ty + i) * 1024 + r0 + tx] =
                __float2half_rn(tile[tx][ty + i]);
    } else if (bid < 1280) {
        int g = (bid - 1024) * 256 + t;  // 0..65535
        int br = g >> 15;
        int rem = g & 32767;
        int ct = rem >> 9;
        int kt = (rem >> 6) & 7;
        int l  = rem & 63;
        int col = ct * 16 + (l & 15);
        int ks  = kt * 32 + (l >> 4) * 8;
        const float* lw = (br ? si_lw : so_lw) + (size_t)col * 256 + ks;
        float4 v0 = *(const float4*)lw;
        float4 v1 = *(const float4*)(lw + 4);
        unsigned hh[8], ll[8];
#pragma unroll
        for (int j = 0; j < 8; ++j) {
            float a = j < 4 ? (&v0.x)[j] : (&v1.x)[j - 4];
            unsigned b = __float_as_uint(a);
            unsigned rh = (b + 0x7FFFu + ((b >> 16) & 1u)) & 0xFFFF0000u;
            hh[j] = rh >> 16;
            float res = a - __uint_as_float(rh);
            unsigned c = __float_as_uint(res);
            unsigned rl = (c + 0x7FFFu + ((c >> 16) & 1u)) & 0xFFFF0000u;
            ll[j] = rl >> 16;
        }
        uint4 ph, pl;
        ph.x = hh[0] | (hh[1] << 16); ph.y = hh[2] | (hh[3] << 16);
        ph.z = hh[4] | (hh[5] << 16); ph.w = hh[6] | (hh[7] << 16);
        pl.x = ll[0] | (ll[1] << 16); pl.y = ll[2] | (ll[3] << 16);
        pl.z = ll[4] | (ll[5] << 16); pl.w = ll[6] | (ll[7] << 16);
        size_t base = (((((size_t)br * 2 + 0) * 64 + ct) * 8 + kt) * 64 + l) * 8;
        size_t hstride = (size_t)64 * 8 * 64 * 8;
        *(uint4*)&whl[base]           = ph;
        *(uint4*)&whl[base + hstride] = pl;
    } else {
        int g = t;                     // channel 0..255
        int n0 = (bid - 1280) * 16;    // 256 blocks x 16 rows
        float4 wo = ((const float4*)so_cw)[g]; float bo = so_cb[g];
        float4 wi = ((const float4*)si_cw)[g]; float bi = si_cb[g];
        float so_s = 0.f, so_q = 0.f, si_s = 0.f, si_q = 0.f;
#pragma unroll
        for (int r = 0; r < 16; ++r) {
            int n = n0 + r;
            float4 xv = ((const float4*)x)[n * 256 + g];
            float co = fmaf(xv.x, wo.x, fmaf(xv.y, wo.y, fmaf(xv.z, wo.z, fmaf(xv.w, wo.w, bo))));
            float ci = fmaf(xv.x, wi.x, fmaf(xv.y, wi.y, fmaf(xv.z, wi.z, fmaf(xv.w, wi.w, bi))));
            xc[n * 256 + g] = co;
            xc[1048576 + n * 256 + g] = ci;
            so_s += co; so_q += co * co;
            si_s += ci; si_q += ci * ci;
        }
        int b = bid - 1280;
        partials[(b * 4 + 0) * 256 + g] = so_s;
        partials[(b * 4 + 1) * 256 + g] = so_q;
        partials[(b * 4 + 2) * 256 + g] = si_s;
        partials[(b * 4 + 3) * 256 + g] = si_q;
    }
}

// ---------------- finalize BN stats -> per-channel scale/shift ---------------
__global__ __launch_bounds__(256) void stats_k(
    const float* __restrict__ partials,
    const float* __restrict__ g_so, const float* __restrict__ b_so,
    const float* __restrict__ g_si, const float* __restrict__ b_si,
    float* __restrict__ sc) {
    int g = threadIdx.x;
    int br = blockIdx.x;  // 0 = so, 1 = si
    float s = 0.f, q = 0.f;
    for (int b = 0; b < 256; ++b) {
        s += partials[(b * 4 + br * 2 + 0) * 256 + g];
        q += partials[(b * 4 + br * 2 + 1) * 256 + g];
    }
    float mean = s * (1.f / 4096.f);
    float var  = q * (1.f / 4096.f) - mean * mean;  // biased, matches ref
    float rstd = rsqrtf(var + 1e-5f);
    float gm = br ? g_si[g] : g_so[g];
    float bt = br ? b_si[g] : b_so[g];
    float scale = gm * rstd;
    sc[br * 512 + g]       = scale;
    sc[br * 512 + 256 + g] = fmaf(-mean, scale, bt);
}

// ---------------- BN + exact GELU + bf16 hi/lo split -> xa MFMA A-fragments --
__global__ __launch_bounds__(256) void gelusplit_k(
    const float* __restrict__ xc, const float* __restrict__ sc,
    unsigned short* __restrict__ xah, unsigned short* __restrict__ xal) {
    int s = blockIdx.x * 256 + threadIdx.x;  // 0..262143
    int br  = s >> 17;
    int rem = s & 131071;
    int rtg = rem >> 9;
    int kt  = (rem >> 6) & 7;
    int l   = rem & 63;
    int row = rtg * 16 + (l & 15);
    int ks  = kt * 32 + (l >> 4) * 8;
    const float* xp  = xc + (size_t)br * 1048576 + (size_t)row * 256 + ks;
    const float* scp = sc + br * 512;
    float4 c0 = *(const float4*)xp;
    float4 c1 = *(const float4*)(xp + 4);
    float4 s0 = *(const float4*)(scp + ks);
    float4 s1 = *(const float4*)(scp + ks + 4);
    float4 h0 = *(const float4*)(scp + 256 + ks);
    float4 h1 = *(const float4*)(scp + 256 + ks + 4);
    unsigned hh[8], ll[8];
#pragma unroll
    for (int j = 0; j < 8; ++j) {
        float cv  = j < 4 ? (&c0.x)[j] : (&c1.x)[j - 4];
        float scl = j < 4 ? (&s0.x)[j] : (&s1.x)[j - 4];
        float shf = j < 4 ? (&h0.x)[j] : (&h1.x)[j - 4];
        float z = fmaf(cv, scl, shf);
        float a = 0.5f * z * (1.f + erff(z * 0.70710678f));
        unsigned b = __float_as_uint(a);
        unsigned rh = (b + 0x7FFFu + ((b >> 16) & 1u)) & 0xFFFF0000u;
        hh[j] = rh >> 16;
        float res = a - __uint_as_float(rh);
        unsigned cc = __float_as_uint(res);
        unsigned rl = (cc + 0x7FFFu + ((cc >> 16) & 1u)) & 0xFFFF0000u;
        ll[j] = rl >> 16;
    }
    uint4 ph, pl;
    ph.x = hh[0] | (hh[1] << 16); ph.y = hh[2] | (hh[3] << 16);
    ph.z = hh[4] | (hh[5] << 16); ph.w = hh[6] | (hh[7] << 16);
    pl.x = ll[0] | (ll[1] << 16); pl.y = ll[2] | (ll[3] << 16);
    pl.z = ll[4] | (ll[5] << 16); pl.w = ll[6] | (ll[7] << 16);
    *(uint4*)&xah[(size_t)s * 8] = ph;
    *(uint4*)&xal[(size_t)s * 8] = pl;
}

// ---------------- bf16x3-split MFMA logits GEMM ------------------------------
__global__ __launch_bounds__(256, 2) void logits_mfma2_k(
    const unsigned short* __restrict__ xah, const unsigned short* __restrict__ xal,
    const unsigned short* __restrict__ whl,
    const float* __restrict__ so_lb, const float* __restrict__ si_lb,
    float* __restrict__ logits) {
    int t = threadIdx.x;
    int bx = blockIdx.x;          // 64-row block
    int n0 = bx * 64;
    int cb = blockIdx.y;          // 256-col block
    int br = blockIdx.z;
    int wave = t >> 6, lane = t & 63;

    f32x4 acc[4][4];  // [ci][rt]
#pragma unroll
    for (int ci = 0; ci < 4; ++ci)
#pragma unroll
        for (int rt = 0; rt < 4; ++rt) acc[ci][rt] = (f32x4){0.f, 0.f, 0.f, 0.f};

    const size_t hstride = (size_t)64 * 8 * 64 * 8;
#pragma unroll 2
    for (int kt = 0; kt < 8; ++kt) {
        short8 Ah[4], Al[4];
#pragma unroll
        for (int rt = 0; rt < 4; ++rt) {
            size_t aoff = (((size_t)br * 256 + bx * 4 + rt) * 8 + kt) * 512 +
                          (size_t)lane * 8;
            Ah[rt] = *(const short8*)&xah[aoff];
            Al[rt] = *(const short8*)&xal[aoff];
        }
#pragma unroll
        for (int ci = 0; ci < 4; ++ci) {
            int ctg = cb * 16 + wave * 4 + ci;
            size_t boff = ((((size_t)br * 2 + 0) * 64 + ctg) * 8 + kt) * 512 +
                          (size_t)lane * 8;
            short8 Wh = *(const short8*)&whl[boff];
            short8 Wl = *(const short8*)&whl[boff + hstride];
#pragma unroll
            for (int rt = 0; rt < 4; ++rt) {
                acc[ci][rt] = __builtin_amdgcn_mfma_f32_16x16x32_bf16(Ah[rt], Wh, acc[ci][rt], 0, 0, 0);
                acc[ci][rt] = __builtin_amdgcn_mfma_f32_16x16x32_bf16(Ah[rt], Wl, acc[ci][rt], 0, 0, 0);
                acc[ci][rt] = __builtin_amdgcn_mfma_f32_16x16x32_bf16(Al[rt], Wh, acc[ci][rt], 0, 0, 0);
            }
        }
    }

    // C/D mapping (HW-verified): col = lane&15, row = (lane>>4)*4 + i
    const float* lb = br ? si_lb : so_lb;
#pragma unroll
    for (int ci = 0; ci < 4; ++ci) {
        int colg = cb * 256 + (wave * 4 + ci) * 16 + (lane & 15);
        float lbv = lb[colg];
#pragma unroll
        for (int rt = 0; rt < 4; ++rt) {
#pragma unroll
            for (int i = 0; i < 4; ++i) {
                int row = n0 + rt * 16 + (lane >> 4) * 4 + i;
                logits[((size_t)br * 4096 + row) * 1024 + colg] = acc[ci][rt][i] + lbv;
            }
        }
    }
}

// ---------------- fused topk + final: 2 rows/block, 1 topk per wave ----------
// Wave w runs the complete barrier-free top-32 for row-branch
// (w&1)*4096 + r0 + (w>>1). 2-LEVEL radix (16-bit prefix); the boundary set is
// resolved by the exact 64-bit (key,~idx) serial argmax (correct for ANY
// boundary size; typically 1-8 elements). exp values computed once.
__global__ __launch_bounds__(256) void topkfinal_k(
    const float* __restrict__ logits, const float* __restrict__ x,
    const __half* __restrict__ wT16, const __half* __restrict__ W16,
    const float* __restrict__ bias, float* __restrict__ out) {
    int t = threadIdx.x, wave = t >> 6, lane = t & 63;
    int r0 = blockIdx.x * 2;
    int ri = wave >> 1;            // this wave's row (0/1)
    int branch = wave & 1;         // 0 = out-branch topk, 1 = in-branch topk
    __shared__ float xr[2][1024];  // output scratch
    __shared__ float dres[2][32];
    __shared__ unsigned int gidx[2][32]; __shared__ float gval[2][32];
    __shared__ unsigned int iidx[2][32]; __shared__ float ival[2][32];
    __shared__ unsigned int hist[4][256];
    __shared__ unsigned int wcnt[4];

    {
        // ================= barrier-free wave-private top-32 =================
        float v[16];
        unsigned int kb[16];
        unsigned int* h = hist[wave];
        const float4* lg =
            (const float4*)(logits + ((size_t)branch * 4096 + r0 + ri) * 1024);
#pragma unroll
        for (int q = 0; q < 4; ++q) {
            float4 f = lg[q * 64 + lane];
            v[q * 4 + 0] = f.x; v[q * 4 + 1] = f.y;
            v[q * 4 + 2] = f.z; v[q * 4 + 3] = f.w;
        }
        float rmax = v[0];
#pragma unroll
        for (int i = 1; i < 16; ++i) rmax = fmaxf(rmax, v[i]);
#pragma unroll
        for (int s = 32; s; s >>= 1) rmax = fmaxf(rmax, __shfl_xor(rmax, s));
#pragma unroll
        for (int i = 0; i < 16; ++i) kb[i] = ford(v[i]);
        // overwrite v with exp values (reused at emit)
        float rsum = 0.f;
#pragma unroll
        for (int i = 0; i < 16; ++i) { v[i] = __expf(v[i] - rmax); rsum += v[i]; }
#pragma unroll
        for (int s = 32; s; s >>= 1) rsum += __shfl_xor(rsum, s);
        float rinv = 1.f / rsum;

        unsigned inmask = 0xFFFFu, need = 32, prefix = 0, lasth = 0;
#pragma unroll
        for (int level = 0; level < 2; ++level) {
            int shift = 24 - level * 8;
            ((uint4*)h)[lane] = make_uint4(0u, 0u, 0u, 0u);
#pragma unroll
            for (int i = 0; i < 16; ++i)
                if ((inmask >> i) & 1u) atomicAdd(&h[(kb[i] >> shift) & 0xFFu], 1u);
            uint4 hv = ((const uint4*)h)[lane];
            unsigned sl = hv.x + hv.y + hv.z + hv.w;
            unsigned S = sl;
#pragma unroll
            for (int off = 1; off < 64; off <<= 1) {
                unsigned o = __shfl_down(S, off);
                if (lane + off < 64) S += o;
            }
            unsigned above = S - sl;
            unsigned cg3 = above + hv.w;
            unsigned cg2 = cg3 + hv.z;
            unsigned cg1 = cg2 + hv.y;
            unsigned cg0 = cg1 + hv.x;
            unsigned pack = 0;
            if      (cg3 >= need) pack = ((4u * lane + 3u) << 12) | cg3;
            else if (cg2 >= need) pack = ((4u * lane + 2u) << 12) | cg2;
            else if (cg1 >= need) pack = ((4u * lane + 1u) << 12) | cg1;
            else if (cg0 >= need) pack = ((4u * lane + 0u) << 12) | cg0;
#pragma unroll
            for (int s = 32; s; s >>= 1) {
                unsigned o = __shfl_xor(pack, s);
                pack = o > pack ? o : pack;
            }
            unsigned bstar = pack >> 12, cstar = pack & 0xFFFu;
            unsigned hstar = h[bstar];
            need -= (cstar - hstar);
            prefix = (prefix << 8) | bstar;
            lasth = hstar;
            unsigned nm = 0;
#pragma unroll
            for (int i = 0; i < 16; ++i)
                if (((inmask >> i) & 1u) && ((kb[i] >> shift) & 0xFFu) == bstar)
                    nm |= 1u << i;
            inmask = nm;
        }

        unsigned winmask = 0;
        if (lasth == need) {
            winmask = inmask;
        } else {
            // exact serial top-`need` over the boundary set, 64-bit (key,~idx)
            unsigned avail = inmask;
            unsigned long long best = 0ULL;
#pragma unroll
            for (int i = 0; i < 16; ++i)
                if ((avail >> i) & 1u) {
                    int j = (i >> 2) * 256 + lane * 4 + (i & 3);
                    unsigned long long k64 =
                        ((unsigned long long)kb[i] << 32) | (unsigned int)(~j);
                    best = k64 > best ? k64 : best;
                }
            for (unsigned k = 0; k < need; ++k) {
                unsigned long long w = best;
#pragma unroll
                for (int s = 32; s; s >>= 1) {
                    unsigned long long o = __shfl_xor(w, s);
                    if (o > w) w = o;
                }
                if (best == w) {
                    unsigned long long nb = 0ULL;
#pragma unroll
                    for (int i = 0; i < 16; ++i)
                        if ((avail >> i) & 1u) {
                            int j = (i >> 2) * 256 + lane * 4 + (i & 3);
                            unsigned long long k64 =
                                ((unsigned long long)kb[i] << 32) | (unsigned int)(~j);
                            if (k64 == w) { winmask |= 1u << i; avail &= ~(1u << i); }
                            else nb = k64 > nb ? k64 : nb;
                        }
                    best = nb;
                }
            }
        }
        if (lane == 0) wcnt[wave] = 0;
        unsigned int* oid = branch ? iidx[ri] : gidx[ri];
        float*        ovl = branch ? ival[ri] : gval[ri];
#pragma unroll
        for (int i = 0; i < 16; ++i) {
            bool wn = ((kb[i] >> 16) > prefix) || ((winmask >> i) & 1u);
            if (wn) {
                unsigned slot = atomicAdd(&wcnt[wave], 1u);
                int j = (i >> 2) * 256 + lane * 4 + (i & 3);
                oid[slot] = (unsigned int)j;
                ovl[slot] = v[i] * rinv;
            }
        }
    }

    // ---- per-lane x of this wave's row in fp16 registers ----
    unsigned int xh[8];
    {
        const float4* xg = (const float4*)(x + (size_t)(r0 + ri) * 1024);
#pragma unroll
        for (int q = 0; q < 2; ++q) {
            float4 xa = xg[(q * 64 + lane) * 2];
            float4 xb = xg[(q * 64 + lane) * 2 + 1];
            xh[q * 4 + 0] = pkrtz(xa.x, xa.y);
            xh[q * 4 + 1] = pkrtz(xa.z, xa.w);
            xh[q * 4 + 2] = pkrtz(xb.x, xb.y);
            xh[q * 4 + 3] = pkrtz(xb.z, xb.w);
        }
    }
    __syncthreads();  // B1: all topk results ready

    if (t < 64) {
        int rr = t >> 5, k = t & 31;
        ival[rr][k] *= x[(size_t)(r0 + rr) * 1024 + iidx[rr][k]];
    }

    // out-branch: 16 gathered fp16 dots per wave (row ri), via v_dot2_f32_f16
#pragma unroll
    for (int d8 = 0; d8 < 16; ++d8) {
        int d = branch * 16 + d8;
        unsigned rowb = (unsigned)__builtin_amdgcn_readfirstlane(gidx[ri][d]);
        const uint4* wrow = (const uint4*)(wT16 + (size_t)rowb * 1024);
        float s = 0.f;
#pragma unroll
        for (int q = 0; q < 2; ++q) {
            uint4 wv = wrow[q * 64 + lane];
            s = __builtin_amdgcn_fdot2(*(const half2_t*)&wv.x,
                                       *(const half2_t*)&xh[q * 4 + 0], s, false);
            s = __builtin_amdgcn_fdot2(*(const half2_t*)&wv.y,
                                       *(const half2_t*)&xh[q * 4 + 1], s, false);
            s = __builtin_amdgcn_fdot2(*(const half2_t*)&wv.z,
                                       *(const half2_t*)&xh[q * 4 + 2], s, false);
            s = __builtin_amdgcn_fdot2(*(const half2_t*)&wv.w,
                                       *(const half2_t*)&xh[q * 4 + 3], s, false);
        }
#pragma unroll
        for (int sft = 32; sft; sft >>= 1) s += __shfl_xor(s, sft);
        if (lane == 0) dres[ri][d] = s * gval[ri][d];
    }
    __syncthreads();  // B2: ival final, dres written

    // in-branch + bias: thread t owns 8 cols of row (t>>7)
    {
        int rr = t >> 7, j0 = (t & 127) * 8;
        float4 accA = *(const float4*)&bias[j0];
        float4 accB = *(const float4*)&bias[j0 + 4];
        for (int k = 0; k < 32; ++k) {
            float g = ival[rr][k];
            unsigned c = (unsigned)__builtin_amdgcn_readfirstlane(iidx[rr][k]);
            uint4 wv = *(const uint4*)(W16 + (size_t)c * 1024 + j0);
            float2 f0 = __half22float2(*(const __half2*)&wv.x);
            float2 f1 = __half22float2(*(const __half2*)&wv.y);
            float2 f2 = __half22float2(*(const __half2*)&wv.z);
            float2 f3 = __half22float2(*(const __half2*)&wv.w);
            accA.x = fmaf(g, f0.x, accA.x); accA.y = fmaf(g, f0.y, accA.y);
            accA.z = fmaf(g, f1.x, accA.z); accA.w = fmaf(g, f1.y, accA.w);
            accB.x = fmaf(g, f2.x, accB.x); accB.y = fmaf(g, f2.y, accB.y);
            accB.z = fmaf(g, f3.x, accB.z); accB.w = fmaf(g, f3.y, accB.w);
        }
        *(float4*)&xr[rr][j0]     = accA;
        *(float4*)&xr[rr][j0 + 4] = accB;
    }
    __syncthreads();  // B3
    if (t < 64) {
        int rr = t >> 5, d = t & 31;
        xr[rr][gidx[rr][d]] += dres[rr][d];  // unique indices, no race
    }
    __syncthreads();  // B4
    {
        int rr = t >> 7, j0 = (t & 127) * 8;
        float* op = out + (size_t)(r0 + rr) * 1024 + j0;
        *(float4*)op       = *(const float4*)&xr[rr][j0];
        *(float4*)(op + 4) = *(const float4*)&xr[rr][j0 + 4];
    }
}

extern "C" void kernel_launch(void* const* d_in, const int* in_sizes, int n_in,
                              void* d_out, int out_size, void* d_ws, size_t ws_size,
                              hipStream_t stream) {
    (void)in_sizes; (void)n_in; (void)out_size; (void)ws_size;
    const float* x        = (const float*)d_in[0];
    const float* W        = (const float*)d_in[1];
    const float* bias     = (const float*)d_in[2];
    const float* so_cw    = (const float*)d_in[3];
    const float* so_cb    = (const float*)d_in[4];
    const float* so_gm    = (const float*)d_in[5];
    const float* so_bt    = (const float*)d_in[6];
    const float* so_lw    = (const float*)d_in[7];
    const float* so_lb    = (const float*)d_in[8];
    const float* si_cw    = (const float*)d_in[9];
    const float* si_cb    = (const float*)d_in[10];
    const float* si_gm    = (const float*)d_in[11];
    const float* si_bt    = (const float*)d_in[12];
    const float* si_lw    = (const float*)d_in[13];
    const float* si_lb    = (const float*)d_in[14];
    float* out = (float*)d_out;

    float* ws       = (float*)d_ws;
    __half* wT16    = (__half*)ws;                      // 1M halves (2MB)
    __half* W16     = (__half*)(ws + 524288);           // 1M halves (2MB)
    unsigned short* whl = (unsigned short*)(ws + 1048576);  // 1M ushorts
    float* xc       = ws + 1572864;             // 2 x 1048576
    float* partials = ws + 3670016;             // 262144
    float* sc       = ws + 3932160;             // 1024
    float* logits   = ws + 3933184;             // 8388608
    unsigned short* xah = (unsigned short*)(ws + 12321792);  // 2097152 ushorts
    unsigned short* xal = (unsigned short*)(ws + 13370368);  // 2097152 ushorts

    prep_k<<<1536, 256, 0, stream>>>(W, so_lw, si_lw, x, so_cw, so_cb, si_cw, si_cb,
                                     wT16, W16, whl, xc, partials);
    stats_k<<<2, 256, 0, stream>>>(partials, so_gm, so_bt, si_gm, si_bt, sc);
    gelusplit_k<<<1024, 256, 0, stream>>>(xc, sc, xah, xal);
    logits_mfma2_k<<<dim3(64, 4, 2), 256, 0, stream>>>(xah, xal, whl, so_lb, si_lb, logits);
    topkfinal_k<<<2048, 256, 0, stream>>>(logits, x, wT16, W16, bias, out);
}